// Round 4
// baseline (972.473 us; speedup 1.0000x reference)
//
#include <hip/hip_runtime.h>
#include <hip/hip_bf16.h>

// GraphNetwork GAT: B=4, N=2048, I=32, H=64, O=32, E=2, HD=2, D1=256
// Inputs fp32, output fp32. R4: occupancy+prefetch rework of mac (TI=8, grid 1024,
// Z=m+lnS folding, 2 barriers/tile), wave-amortized wh_a (8 bn/wave, scalar state loads).

constexpr int B_  = 4;
constexpr int N_  = 2048;
constexpr int I_  = 32;
constexpr int H_  = 64;
constexpr int O_  = 32;
constexpr int EH_ = 4;        // E*HD combos, c = e*2 + h
constexpr int D1_ = 256;      // H*HD*E
constexpr int BN_ = B_ * N_;  // 8192
constexpr int NC_ = 16;       // i-chunks for softmax stats
constexpr int CH_ = N_ / NC_; // 128
constexpr int TI_ = 8;        // msg rows per block in MAC sweep
constexpr int TK_ = 32;       // k-tile in MAC sweep
constexpr int NKT_ = N_ / TK_; // 64 k-tiles

__device__ __forceinline__ float lrelu(float x) { return fmaxf(x, 0.2f * x); }

// ---------------------------------------------------------------- embedding
__global__ __launch_bounds__(256) void embed_kernel(
        const float* __restrict__ nodes, const float* __restrict__ W_emb,
        const float* __restrict__ b_emb, float* __restrict__ state0) {
    int t = threadIdx.x;                 // 256
    int r = t >> 6, h = t & 63;
    int bn = blockIdx.x * 4 + r;
    __shared__ float sn[4][I_];
    if (t < 4 * I_) {
        int rr = t / I_, ii = t % I_;
        sn[rr][ii] = nodes[(size_t)(blockIdx.x * 4 + rr) * I_ + ii];
    }
    __syncthreads();
    float acc = b_emb[h];
    #pragma unroll
    for (int i = 0; i < I_; ++i) acc += sn[r][i] * W_emb[i * H_ + h];
    state0[(size_t)bn * H_ + h] = acc;
}

// ---------------------------------------------------- Wh + attention logits
// 8 bn per wave: Wf row loaded once per wave (not once per bn); state via
// wave-uniform scalar loads. Wh[c,bn,k]; a1/a2 = Wh.w1/w2 + b1/b2.
template <int DIN>
__global__ __launch_bounds__(256) void wh_a_kernel(
        const float* __restrict__ state, const float* __restrict__ Wf,
        const float* __restrict__ w1, const float* __restrict__ b1,
        const float* __restrict__ w2, const float* __restrict__ b2,
        float* __restrict__ Wh, float* __restrict__ a1, float* __restrict__ a2) {
    int t = threadIdx.x;
    int w = t >> 6;                // wave 0..3
    int k = t & 63;
    int blk = blockIdx.x;          // EH * (BN/32) = 1024
    int c = blk >> 8;
    int bn0 = (blk & 255) * 32 + w * 8;
    const float* __restrict__ wf = Wf + (size_t)c * DIN * H_;
    float acc[8] = {};
    #pragma unroll 2
    for (int d0 = 0; d0 < DIN; d0 += 4) {
        float wv0 = wf[(d0 + 0) * H_ + k];
        float wv1 = wf[(d0 + 1) * H_ + k];
        float wv2 = wf[(d0 + 2) * H_ + k];
        float wv3 = wf[(d0 + 3) * H_ + k];
        #pragma unroll
        for (int j = 0; j < 8; ++j) {
            const float* sp = state + (size_t)(bn0 + j) * DIN + d0;  // wave-uniform -> s_load
            float s0 = sp[0], s1 = sp[1], s2 = sp[2], s3 = sp[3];
            acc[j] += wv0 * s0 + wv1 * s1 + wv2 * s2 + wv3 * s3;
        }
    }
    float w1k = w1[c * H_ + k], w2k = w2[c * H_ + k];
    float b1c = b1[c], b2c = b2[c];
    #pragma unroll
    for (int j = 0; j < 8; ++j) {
        Wh[((size_t)c * BN_ + bn0 + j) * H_ + k] = acc[j];
        float t1 = acc[j] * w1k, t2 = acc[j] * w2k;
        #pragma unroll
        for (int m = 32; m; m >>= 1) { t1 += __shfl_xor(t1, m, 64); t2 += __shfl_xor(t2, m, 64); }
        if (k == 0) {
            a1[(size_t)c * BN_ + bn0 + j] = t1 + b1c;
            a2[(size_t)c * BN_ + bn0 + j] = t2 + b2c;
        }
    }
}

// -------------------------------------------------- column softmax stats
// online (m,s) over i-chunk for each (c,b,j); l = lrelu(a1[i]+a2[j]) + edges[b,i,j,e]
__global__ __launch_bounds__(256) void stats_kernel(
        const float* __restrict__ edges, const float* __restrict__ a1,
        const float* __restrict__ a2, float* __restrict__ pm, float* __restrict__ ps) {
    int blk = blockIdx.x;                       // B*NC*(N/256) = 512
    int jt = blk & 7;
    int ic = (blk >> 3) & (NC_ - 1);
    int b  = blk >> 7;
    int t = threadIdx.x;
    int j = jt * 256 + t;
    __shared__ float sa1[EH_][CH_];
    for (int q = t; q < EH_ * CH_; q += 256) {
        int cc = q / CH_, ii = q % CH_;
        sa1[cc][ii] = a1[(size_t)cc * BN_ + b * N_ + ic * CH_ + ii];
    }
    __syncthreads();
    float a2v[EH_], m[EH_], s[EH_];
    #pragma unroll
    for (int cc = 0; cc < EH_; ++cc) {
        a2v[cc] = a2[(size_t)cc * BN_ + b * N_ + j];
        m[cc] = -1e30f; s[cc] = 0.f;
    }
    const float2* __restrict__ ep = (const float2*)edges + ((size_t)(b * N_ + ic * CH_)) * N_ + j;
    #pragma unroll 2
    for (int ii = 0; ii < CH_; ++ii) {
        float2 u = ep[(size_t)ii * N_];
        #pragma unroll
        for (int cc = 0; cc < EH_; ++cc) {
            float x = sa1[cc][ii] + a2v[cc];
            float l = lrelu(x) + ((cc < 2) ? u.x : u.y);
            float mn = fmaxf(m[cc], l);
            s[cc] = s[cc] * __expf(m[cc] - mn) + __expf(l - mn);
            m[cc] = mn;
        }
    }
    #pragma unroll
    for (int cc = 0; cc < EH_; ++cc) {
        size_t q = ((size_t)ic * EH_ + cc) * BN_ + b * N_ + j;
        pm[q] = m[cc]; ps[q] = s[cc];
    }
}

// combine partials; emit packed (Z = m + lnS, a2) so mac needs one b64 per (c,k)
__global__ __launch_bounds__(256) void combine_kernel(
        const float* __restrict__ pm, const float* __restrict__ ps,
        const float* __restrict__ a2, float2* __restrict__ za) {
    int q = blockIdx.x * 256 + threadIdx.x;     // EH*BN = 32768
    float M = -1e30f;
    #pragma unroll
    for (int ic = 0; ic < NC_; ++ic) M = fmaxf(M, pm[(size_t)ic * EH_ * BN_ + q]);
    float S = 0.f;
    #pragma unroll
    for (int ic = 0; ic < NC_; ++ic)
        S += ps[(size_t)ic * EH_ * BN_ + q] * __expf(pm[(size_t)ic * EH_ * BN_ + q] - M);
    za[q] = make_float2(M + __logf(S), a2[q]);
}

// ------------------------------------------------------------- MAC sweep
// msg[c,b,i,d] = sum_k att[c,b,i,k]*Wh[c,b,k,d]; att = exp(l - Z[k]) on the fly.
// TI=8 rows/block, 256 thr (wave c), grid B*(N/8)=1024 -> 4 blocks/CU.
// Register prefetch of next tile's edges+za across the MAC phase.
template <int LAST>
__global__ __launch_bounds__(256, 4) void mac_kernel(
        const float* __restrict__ edges, const float* __restrict__ a1,
        const float2* __restrict__ za, const float* __restrict__ Wh,
        const float* __restrict__ bias, float* __restrict__ out) {
    int t = threadIdx.x;                    // 256
    int blk = blockIdx.x;                   // B*(N/TI) = 1024
    int b = blk >> 8;
    int i0 = (blk & 255) * TI_;
    int c = t >> 6;                         // wave id = eh combo
    int g = t & 63;
    int dg = g >> 2, ig = g & 3;
    int d0 = dg * 4;
    int il = (t >> 5) & 7;                  // edge-phase row 0..7
    int kl = t & 31;                        // edge-phase col 0..31

    __shared__ float satt[EH_][TK_][10];    // row stride 10: 2-way on write (free), bcast read
    __shared__ float sred[EH_][TI_][H_];    // LAST epilogue

    float a1v[EH_];
    #pragma unroll
    for (int cc = 0; cc < EH_; ++cc)
        a1v[cc] = a1[(size_t)cc * BN_ + b * N_ + i0 + il];

    const float2* __restrict__ ep = (const float2*)edges + (size_t)(b * N_ + i0 + il) * N_;
    // preload tile 0
    float2 ev = ep[kl];
    float2 zv[EH_];
    #pragma unroll
    for (int cc = 0; cc < EH_; ++cc) zv[cc] = za[(size_t)cc * BN_ + b * N_ + kl];

    float acc[4][2] = {};                   // [di][ii]

    for (int kt = 0; kt < NKT_; ++kt) {
        int k0 = kt * TK_;
        // ---- att for this tile from preloaded regs
        #pragma unroll
        for (int cc = 0; cc < EH_; ++cc) {
            float x = a1v[cc] + zv[cc].y;
            float l = lrelu(x) + ((cc < 2) ? ev.x : ev.y);
            satt[cc][kl][il] = __expf(l - zv[cc].x);
        }
        // ---- prefetch next tile (wraps harmlessly on last iter)
        int kn = ((kt + 1) & (NKT_ - 1)) * TK_ + kl;
        float2 ev2 = ep[kn];
        float2 zv2[EH_];
        #pragma unroll
        for (int cc = 0; cc < EH_; ++cc) zv2[cc] = za[(size_t)cc * BN_ + b * N_ + kn];
        __syncthreads();
        // ---- MAC
        const float* __restrict__ whp = Wh + ((size_t)c * BN_ + b * N_ + k0) * H_ + d0;
        #pragma unroll 8
        for (int kk = 0; kk < TK_; ++kk) {
            float2 av = *(const float2*)&satt[c][kk][ig * 2];
            float4 w  = *(const float4*)(whp + (size_t)kk * H_);
            acc[0][0] += w.x * av.x; acc[0][1] += w.x * av.y;
            acc[1][0] += w.y * av.x; acc[1][1] += w.y * av.y;
            acc[2][0] += w.z * av.x; acc[2][1] += w.z * av.y;
            acc[3][0] += w.w * av.x; acc[3][1] += w.w * av.y;
        }
        __syncthreads();
        ev = ev2;
        #pragma unroll
        for (int cc = 0; cc < EH_; ++cc) zv[cc] = zv2[cc];
    }

    float bv[4];
    #pragma unroll
    for (int di = 0; di < 4; ++di) bv[di] = bias[(c & 1) * H_ + d0 + di];

    if (LAST) {
        #pragma unroll
        for (int ii = 0; ii < 2; ++ii)
            #pragma unroll
            for (int di = 0; di < 4; ++di)
                sred[c][ig * 2 + ii][d0 + di] = acc[di][ii] + bv[di];
        __syncthreads();
        #pragma unroll
        for (int p = t; p < TI_ * H_; p += 256) {
            int r = p >> 6, d = p & 63;
            float s = 0.f;
            #pragma unroll
            for (int cc = 0; cc < EH_; ++cc) {
                float x = sred[cc][r][d];
                s += x > 0.f ? x : (__expf(x) - 1.f);
            }
            out[((size_t)b * N_ + i0 + r) * H_ + d] = s * 0.25f;
        }
    } else {
        #pragma unroll
        for (int ii = 0; ii < 2; ++ii) {
            float4 v = make_float4(acc[0][ii] + bv[0], acc[1][ii] + bv[1],
                                   acc[2][ii] + bv[2], acc[3][ii] + bv[3]);
            *(float4*)(out + ((size_t)b * N_ + i0 + ig * 2 + ii) * D1_ + c * H_ + d0) = v;
        }
    }
}

// ------------------------------------------------------------- final output
__global__ __launch_bounds__(256) void out_kernel(
        const float* __restrict__ state2, const float* __restrict__ W_out,
        const float* __restrict__ b_out, float* __restrict__ out) {
    int b = blockIdx.x, t = threadIdx.x;    // 256
    int d = t & 63, nc = t >> 6;
    float psum = 0.f;
    const float* sp = state2 + ((size_t)b * N_ + nc * (N_ / 4)) * H_ + d;
    for (int n = 0; n < N_ / 4; ++n) psum += sp[(size_t)n * H_];
    __shared__ float red[4][H_];
    red[nc][d] = psum;
    __syncthreads();
    if (t < H_) red[0][d] = red[0][d] + red[1][d] + red[2][d] + red[3][d];
    __syncthreads();
    if (t < O_) {
        float acc = b_out[t];
        #pragma unroll 8
        for (int dd = 0; dd < H_; ++dd)
            acc += (red[0][dd] * (1.f / N_)) * W_out[dd * O_ + t];
        out[b * O_ + t] = acc;
    }
}

extern "C" void kernel_launch(void* const* d_in, const int* in_sizes, int n_in,
                              void* d_out, int out_size, void* d_ws, size_t ws_size,
                              hipStream_t stream) {
    const float* nodes = (const float*)d_in[0];
    const float* edges = (const float*)d_in[1];
    const float* W_emb = (const float*)d_in[2];
    const float* b_emb = (const float*)d_in[3];
    const float* Wf0   = (const float*)d_in[4];
    const float* w1_0  = (const float*)d_in[5];
    const float* b1_0  = (const float*)d_in[6];
    const float* w2_0  = (const float*)d_in[7];
    const float* b2_0  = (const float*)d_in[8];
    const float* bias0 = (const float*)d_in[9];
    const float* Wf1   = (const float*)d_in[10];
    const float* w1_1  = (const float*)d_in[11];
    const float* b1_1  = (const float*)d_in[12];
    const float* w2_1  = (const float*)d_in[13];
    const float* b2_1  = (const float*)d_in[14];
    const float* bias1 = (const float*)d_in[15];
    const float* W_out = (const float*)d_in[16];
    const float* b_out = (const float*)d_in[17];

    float* ws     = (float*)d_ws;
    float* state0 = ws;                          // B*N*H      = 524288
    float* state1 = state0 + 524288;             // B*N*D1     = 2097152
    float* state2 = state1 + 2097152;            // B*N*H      = 524288
    float* Wh     = state2 + 524288;             // EH*B*N*H   = 2097152
    float* a1     = Wh + 2097152;                // EH*B*N     = 32768
    float* a2     = a1 + 32768;
    float* pm     = a2 + 32768;                  // NC*EH*B*N  = 524288
    float* psum   = pm + 524288;
    float2* za    = (float2*)(psum + 524288);    // EH*B*N float2 = 65536 floats

    embed_kernel<<<BN_ / 4, 256, 0, stream>>>(nodes, W_emb, b_emb, state0);

    // ---- layer 0
    wh_a_kernel<H_><<<EH_ * (BN_ / 32), 256, 0, stream>>>(state0, Wf0, w1_0, b1_0,
                                                          w2_0, b2_0, Wh, a1, a2);
    stats_kernel<<<B_ * NC_ * (N_ / 256), 256, 0, stream>>>(edges, a1, a2, pm, psum);
    combine_kernel<<<EH_ * BN_ / 256, 256, 0, stream>>>(pm, psum, a2, za);
    mac_kernel<0><<<B_ * (N_ / TI_), 256, 0, stream>>>(edges, a1, za, Wh, bias0, state1);
    // ---- layer 1
    wh_a_kernel<D1_><<<EH_ * (BN_ / 32), 256, 0, stream>>>(state1, Wf1, w1_1, b1_1,
                                                           w2_1, b2_1, Wh, a1, a2);
    stats_kernel<<<B_ * NC_ * (N_ / 256), 256, 0, stream>>>(edges, a1, a2, pm, psum);
    combine_kernel<<<EH_ * BN_ / 256, 256, 0, stream>>>(pm, psum, a2, za);
    mac_kernel<1><<<B_ * (N_ / TI_), 256, 0, stream>>>(edges, a1, za, Wh, bias1, state2);

    out_kernel<<<B_, 256, 0, stream>>>(state2, W_out, b_out, (float*)d_out);
}

// Round 5
// 520.669 us; speedup vs baseline: 1.8677x; 1.8677x over previous
//
#include <hip/hip_runtime.h>
#include <hip/hip_bf16.h>

// GraphNetwork GAT: B=4, N=2048, I=32, H=64, O=32, E=2, HD=2, D1=256
// R5: MFMA mac kernel. att->bf16 in LDS (frag layout), Wh pre-packed bf16
// B-fragments, single barrier/k-step, 2-deep edge prefetch. Wh fp32 dropped.

constexpr int B_  = 4;
constexpr int N_  = 2048;
constexpr int I_  = 32;
constexpr int H_  = 64;
constexpr int O_  = 32;
constexpr int EH_ = 4;          // E*HD combos, c = e*2 + h
constexpr int D1_ = 256;        // H*HD*E
constexpr int BN_ = B_ * N_;    // 8192
constexpr int NC_ = 16;         // i-chunks for softmax stats
constexpr int CH_ = N_ / NC_;   // 128
constexpr int TI_ = 16;         // msg rows per block (one MFMA m-tile)
constexpr int TK_ = 32;         // k-tile (one MFMA K)
constexpr int NKT_ = N_ / TK_;  // 64 k-tiles

typedef __bf16 bf16x8 __attribute__((ext_vector_type(8)));
typedef float floatx4 __attribute__((ext_vector_type(4)));

__device__ __forceinline__ unsigned short f2b(float f) {
    unsigned int u = __float_as_uint(f);
    return (unsigned short)((u + 0x7fffu + ((u >> 16) & 1u)) >> 16);
}
__device__ __forceinline__ float lrelu(float x) { return fmaxf(x, 0.2f * x); }

// ---------------------------------------------------------------- embedding
__global__ __launch_bounds__(256) void embed_kernel(
        const float* __restrict__ nodes, const float* __restrict__ W_emb,
        const float* __restrict__ b_emb, float* __restrict__ state0) {
    int t = threadIdx.x;
    int r = t >> 6, h = t & 63;
    int bn = blockIdx.x * 4 + r;
    __shared__ float sn[4][I_];
    if (t < 4 * I_) {
        int rr = t / I_, ii = t % I_;
        sn[rr][ii] = nodes[(size_t)(blockIdx.x * 4 + rr) * I_ + ii];
    }
    __syncthreads();
    float acc = b_emb[h];
    #pragma unroll
    for (int i = 0; i < I_; ++i) acc += sn[r][i] * W_emb[i * H_ + h];
    state0[(size_t)bn * H_ + h] = acc;
}

// ---------------------------------------------------- Wh + attention logits
// 8 bn per wave; Wh written in bf16 B-fragment layout:
// WhB[c][b][n>>3][d][n&7]  (lane's 8 contraction values contiguous, 16B)
template <int DIN>
__global__ __launch_bounds__(256) void wh_a_kernel(
        const float* __restrict__ state, const float* __restrict__ Wf,
        const float* __restrict__ w1, const float* __restrict__ b1,
        const float* __restrict__ w2, const float* __restrict__ b2,
        unsigned short* __restrict__ WhB, float* __restrict__ a1,
        float* __restrict__ a2) {
    int t = threadIdx.x;
    int w = t >> 6;                // wave 0..3
    int k = t & 63;                // d index
    int blk = blockIdx.x;          // EH * (BN/32) = 1024
    int c = blk >> 8;
    int bn0 = (blk & 255) * 32 + w * 8;
    const float* __restrict__ wf = Wf + (size_t)c * DIN * H_;
    float acc[8] = {};
    #pragma unroll 2
    for (int d0 = 0; d0 < DIN; d0 += 4) {
        float wv0 = wf[(d0 + 0) * H_ + k];
        float wv1 = wf[(d0 + 1) * H_ + k];
        float wv2 = wf[(d0 + 2) * H_ + k];
        float wv3 = wf[(d0 + 3) * H_ + k];
        #pragma unroll
        for (int j = 0; j < 8; ++j) {
            const float* sp = state + (size_t)(bn0 + j) * DIN + d0;  // wave-uniform
            acc[j] += wv0 * sp[0] + wv1 * sp[1] + wv2 * sp[2] + wv3 * sp[3];
        }
    }
    // packed bf16 store: b = bn0>>11, nb = (bn0&2047)>>3
    {
        int b = bn0 >> 11, nb = (bn0 & 2047) >> 3;
        union { unsigned short s[8]; uint4 v; } pk;
        #pragma unroll
        for (int j = 0; j < 8; ++j) pk.s[j] = f2b(acc[j]);
        *(uint4*)(WhB + (((size_t)(c * B_ + b) * 256 + nb) * 64 + k) * 8) = pk.v;
    }
    float w1k = w1[c * H_ + k], w2k = w2[c * H_ + k];
    float b1c = b1[c], b2c = b2[c];
    #pragma unroll
    for (int j = 0; j < 8; ++j) {
        float t1 = acc[j] * w1k, t2 = acc[j] * w2k;
        #pragma unroll
        for (int m = 32; m; m >>= 1) { t1 += __shfl_xor(t1, m, 64); t2 += __shfl_xor(t2, m, 64); }
        if (k == 0) {
            a1[(size_t)c * BN_ + bn0 + j] = t1 + b1c;
            a2[(size_t)c * BN_ + bn0 + j] = t2 + b2c;
        }
    }
}

// -------------------------------------------------- column softmax stats
__global__ __launch_bounds__(256) void stats_kernel(
        const float* __restrict__ edges, const float* __restrict__ a1,
        const float* __restrict__ a2, float* __restrict__ pm, float* __restrict__ ps) {
    int blk = blockIdx.x;                       // B*NC*(N/256) = 512
    int jt = blk & 7;
    int ic = (blk >> 3) & (NC_ - 1);
    int b  = blk >> 7;
    int t = threadIdx.x;
    int j = jt * 256 + t;
    __shared__ float sa1[EH_][CH_];
    for (int q = t; q < EH_ * CH_; q += 256) {
        int cc = q / CH_, ii = q % CH_;
        sa1[cc][ii] = a1[(size_t)cc * BN_ + b * N_ + ic * CH_ + ii];
    }
    __syncthreads();
    float a2v[EH_], m[EH_], s[EH_];
    #pragma unroll
    for (int cc = 0; cc < EH_; ++cc) {
        a2v[cc] = a2[(size_t)cc * BN_ + b * N_ + j];
        m[cc] = -1e30f; s[cc] = 0.f;
    }
    const float2* __restrict__ ep = (const float2*)edges + ((size_t)(b * N_ + ic * CH_)) * N_ + j;
    #pragma unroll 2
    for (int ii = 0; ii < CH_; ++ii) {
        float2 u = ep[(size_t)ii * N_];
        #pragma unroll
        for (int cc = 0; cc < EH_; ++cc) {
            float x = sa1[cc][ii] + a2v[cc];
            float l = lrelu(x) + ((cc < 2) ? u.x : u.y);
            float mn = fmaxf(m[cc], l);
            s[cc] = s[cc] * __expf(m[cc] - mn) + __expf(l - mn);
            m[cc] = mn;
        }
    }
    #pragma unroll
    for (int cc = 0; cc < EH_; ++cc) {
        size_t q = ((size_t)ic * EH_ + cc) * BN_ + b * N_ + j;
        pm[q] = m[cc]; ps[q] = s[cc];
    }
}

// combine partials -> za[c][bn] = (Z = m + lnS, a2)
__global__ __launch_bounds__(256) void combine_kernel(
        const float* __restrict__ pm, const float* __restrict__ ps,
        const float* __restrict__ a2, float2* __restrict__ za) {
    int q = blockIdx.x * 256 + threadIdx.x;     // EH*BN = 32768
    float M = -1e30f;
    #pragma unroll
    for (int ic = 0; ic < NC_; ++ic) M = fmaxf(M, pm[(size_t)ic * EH_ * BN_ + q]);
    float S = 0.f;
    #pragma unroll
    for (int ic = 0; ic < NC_; ++ic)
        S += ps[(size_t)ic * EH_ * BN_ + q] * __expf(pm[(size_t)ic * EH_ * BN_ + q] - M);
    za[q] = make_float2(M + __logf(S), a2[q]);
}

// ------------------------------------------------------------- MFMA MAC
// Block: (b, 16 rows i), 4 waves = 4 c. Per k-step: all threads compute
// att (bf16) into LDS frag layout; wave c does 4x mfma_16x16x32_bf16
// against pre-packed WhB. Single barrier/k-step (double-buffered satt/szq).
template <int LAST>
__global__ __launch_bounds__(256, 4) void mac_kernel(
        const float* __restrict__ edges, const float* __restrict__ a1,
        const float2* __restrict__ za, const unsigned short* __restrict__ WhB,
        const float* __restrict__ bias, float* __restrict__ out) {
    int t = threadIdx.x;                    // 256
    int blk = blockIdx.x;                   // B*(N/16) = 512
    int b = blk >> 7;
    int i0 = (blk & 127) * TI_;
    int lane = t & 63, wv = t >> 6;         // wave id = c
    int ai = t >> 4;                        // att row 0..15
    int ak = (t & 15) * 2;                  // att k (even) 0..30
    int qd = lane >> 4;                     // quad
    int col = lane & 15;

    __shared__ unsigned short satt[2][EH_][TI_][40];  // stride 40: 2-way max (free)
    __shared__ float2 szq[2][EH_][TK_];
    __shared__ float sred[EH_][TI_][H_];              // LAST epilogue

    float a1v[EH_];
    #pragma unroll
    for (int cc = 0; cc < EH_; ++cc)
        a1v[cc] = a1[(size_t)cc * BN_ + b * N_ + i0 + ai];

    const float4* __restrict__ ep =
        (const float4*)edges + (size_t)(b * N_ + i0 + ai) * (N_ >> 1);
    // prefetch edges for k-steps 0 and 1; stage za for step 0
    float4 ev0 = ep[(ak >> 1)];
    float4 ev1 = ep[(TK_ >> 1) + (ak >> 1)];
    if (t < 128) {
        int cc = t >> 5, kk = t & 31;
        szq[0][cc][kk] = za[(size_t)cc * BN_ + b * N_ + kk];
    }
    // prefetch B-fragments for step 0
    const unsigned short* __restrict__ whb0 =
        WhB + (size_t)(wv * B_ + b) * (256 * 512);
    bf16x8 bcur[4], bnxt[4];
    #pragma unroll
    for (int nt = 0; nt < 4; ++nt)
        bcur[nt] = *(const bf16x8*)(whb0 + ((size_t)(0 + qd) * 64 + nt * 16 + col) * 8);

    floatx4 acc[4] = {{0,0,0,0},{0,0,0,0},{0,0,0,0},{0,0,0,0}};
    __syncthreads();   // szq[0] visible

    for (int kt = 0; kt < NKT_; ++kt) {
        int cur = kt & 1, nxt = cur ^ 1;
        // stage za for step kt+1
        int k0n = ((kt + 1) & (NKT_ - 1)) * TK_;
        if (t < 128) {
            int cc = t >> 5, kk = t & 31;
            szq[nxt][cc][kk] = za[(size_t)cc * BN_ + b * N_ + k0n + kk];
        }
        // att(kt) from ev0 + szq[cur] -> satt[cur]
        #pragma unroll
        for (int cc = 0; cc < EH_; ++cc) {
            float2 z0 = szq[cur][cc][ak];
            float2 z1 = szq[cur][cc][ak + 1];
            float e0 = (cc < 2) ? ev0.x : ev0.y;
            float e1 = (cc < 2) ? ev0.z : ev0.w;
            float x0 = a1v[cc] + z0.y;
            float x1 = a1v[cc] + z1.y;
            float at0 = __expf(lrelu(x0) + e0 - z0.x);
            float at1 = __expf(lrelu(x1) + e1 - z1.x);
            unsigned int p = (unsigned int)f2b(at0) | ((unsigned int)f2b(at1) << 16);
            *(unsigned int*)&satt[cur][cc][ai][ak] = p;
        }
        // prefetch edges for kt+2
        float4 ev2 = ep[((kt + 2) & (NKT_ - 1)) * (TK_ >> 1) + (ak >> 1)];
        __syncthreads();
        // prefetch B-fragments for kt+1
        int kb = ((kt + 1) & (NKT_ - 1)) * (TK_ >> 3);
        #pragma unroll
        for (int nt = 0; nt < 4; ++nt)
            bnxt[nt] = *(const bf16x8*)(whb0 + ((size_t)(kb + qd) * 64 + nt * 16 + col) * 8);
        // MFMA: A-frag from satt[cur][wv], 4 n-tiles
        bf16x8 af = *(const bf16x8*)&satt[cur][wv][col][qd * 8];
        #pragma unroll
        for (int nt = 0; nt < 4; ++nt)
            acc[nt] = __builtin_amdgcn_mfma_f32_16x16x32_bf16(af, bcur[nt], acc[nt], 0, 0, 0);
        #pragma unroll
        for (int nt = 0; nt < 4; ++nt) bcur[nt] = bnxt[nt];
        ev0 = ev1; ev1 = ev2;
    }

    // epilogue: D layout row = qd*4+reg, col(d) = nt*16 + col
    if (LAST) {
        #pragma unroll
        for (int nt = 0; nt < 4; ++nt) {
            float bv = bias[(wv & 1) * H_ + nt * 16 + col];
            #pragma unroll
            for (int r = 0; r < 4; ++r) {
                float x = acc[nt][r] + bv;
                sred[wv][qd * 4 + r][nt * 16 + col] = x > 0.f ? x : (__expf(x) - 1.f);
            }
        }
        __syncthreads();
        #pragma unroll
        for (int q = 0; q < 4; ++q) {
            int p = t + q * 256;
            int r = p >> 6, d = p & 63;
            float s = sred[0][r][d] + sred[1][r][d] + sred[2][r][d] + sred[3][r][d];
            out[((size_t)(b * N_ + i0 + r)) * H_ + d] = s * 0.25f;
        }
    } else {
        #pragma unroll
        for (int nt = 0; nt < 4; ++nt) {
            float bv = bias[(wv & 1) * H_ + nt * 16 + col];
            #pragma unroll
            for (int r = 0; r < 4; ++r)
                out[((size_t)(b * N_ + i0 + qd * 4 + r)) * D1_ + wv * H_ + nt * 16 + col] =
                    acc[nt][r] + bv;
        }
    }
}

// ------------------------------------------------------------- final output
__global__ __launch_bounds__(256) void out_kernel(
        const float* __restrict__ state2, const float* __restrict__ W_out,
        const float* __restrict__ b_out, float* __restrict__ out) {
    int b = blockIdx.x, t = threadIdx.x;
    int d = t & 63, nc = t >> 6;
    float psum = 0.f;
    const float* sp = state2 + ((size_t)b * N_ + nc * (N_ / 4)) * H_ + d;
    for (int n = 0; n < N_ / 4; ++n) psum += sp[(size_t)n * H_];
    __shared__ float red[4][H_];
    red[nc][d] = psum;
    __syncthreads();
    if (t < H_) red[0][d] = red[0][d] + red[1][d] + red[2][d] + red[3][d];
    __syncthreads();
    if (t < O_) {
        float acc = b_out[t];
        #pragma unroll 8
        for (int dd = 0; dd < H_; ++dd)
            acc += (red[0][dd] * (1.f / N_)) * W_out[dd * O_ + t];
        out[b * O_ + t] = acc;
    }
}

extern "C" void kernel_launch(void* const* d_in, const int* in_sizes, int n_in,
                              void* d_out, int out_size, void* d_ws, size_t ws_size,
                              hipStream_t stream) {
    const float* nodes = (const float*)d_in[0];
    const float* edges = (const float*)d_in[1];
    const float* W_emb = (const float*)d_in[2];
    const float* b_emb = (const float*)d_in[3];
    const float* Wf0   = (const float*)d_in[4];
    const float* w1_0  = (const float*)d_in[5];
    const float* b1_0  = (const float*)d_in[6];
    const float* w2_0  = (const float*)d_in[7];
    const float* b2_0  = (const float*)d_in[8];
    const float* bias0 = (const float*)d_in[9];
    const float* Wf1   = (const float*)d_in[10];
    const float* w1_1  = (const float*)d_in[11];
    const float* b1_1  = (const float*)d_in[12];
    const float* w2_1  = (const float*)d_in[13];
    const float* b2_1  = (const float*)d_in[14];
    const float* bias1 = (const float*)d_in[15];
    const float* W_out = (const float*)d_in[16];
    const float* b_out = (const float*)d_in[17];

    float* ws     = (float*)d_ws;
    float* state0 = ws;                          // 524288
    float* state1 = state0 + 524288;             // 2097152
    float* state2 = state1 + 2097152;            // 524288
    unsigned short* WhB = (unsigned short*)(state2 + 524288);  // EH*B*N*H ushort = 1048576 floats
    float* a1     = state2 + 524288 + 1048576;   // 32768
    float* a2     = a1 + 32768;
    float* pm     = a2 + 32768;                  // 524288
    float* psum   = pm + 524288;
    float2* za    = (float2*)(psum + 524288);    // 65536 floats

    embed_kernel<<<BN_ / 4, 256, 0, stream>>>(nodes, W_emb, b_emb, state0);

    // ---- layer 0
    wh_a_kernel<H_><<<EH_ * (BN_ / 32), 256, 0, stream>>>(state0, Wf0, w1_0, b1_0,
                                                          w2_0, b2_0, WhB, a1, a2);
    stats_kernel<<<B_ * NC_ * (N_ / 256), 256, 0, stream>>>(edges, a1, a2, pm, psum);
    combine_kernel<<<EH_ * BN_ / 256, 256, 0, stream>>>(pm, psum, a2, za);
    mac_kernel<0><<<B_ * (N_ / TI_), 256, 0, stream>>>(edges, a1, za, WhB, bias0, state1);
    // ---- layer 1
    wh_a_kernel<D1_><<<EH_ * (BN_ / 32), 256, 0, stream>>>(state1, Wf1, w1_1, b1_1,
                                                           w2_1, b2_1, WhB, a1, a2);
    stats_kernel<<<B_ * NC_ * (N_ / 256), 256, 0, stream>>>(edges, a1, a2, pm, psum);
    combine_kernel<<<EH_ * BN_ / 256, 256, 0, stream>>>(pm, psum, a2, za);
    mac_kernel<1><<<B_ * (N_ / TI_), 256, 0, stream>>>(edges, a1, za, WhB, bias1, state2);

    out_kernel<<<B_, 256, 0, stream>>>(state2, W_out, b_out, (float*)d_out);
}

// Round 6
// 444.415 us; speedup vs baseline: 2.1882x; 1.1716x over previous
//
#include <hip/hip_runtime.h>
#include <hip/hip_bf16.h>

// GraphNetwork GAT: B=4, N=2048, I=32, H=64, O=32, E=2, HD=2, D1=256
// R6: wh_a -> MFMA GEMM (bf16 state, transposed bf16 Wf, no LDS/barriers),
// bf16 state0/state1, 1-exp online softmax in stats. mac unchanged from R5.

constexpr int B_  = 4;
constexpr int N_  = 2048;
constexpr int I_  = 32;
constexpr int H_  = 64;
constexpr int O_  = 32;
constexpr int EH_ = 4;          // E*HD combos, c = e*2 + h
constexpr int D1_ = 256;        // H*HD*E
constexpr int BN_ = B_ * N_;    // 8192
constexpr int NC_ = 16;         // i-chunks for softmax stats
constexpr int CH_ = N_ / NC_;   // 128
constexpr int TI_ = 16;         // msg rows per block (one MFMA m-tile)
constexpr int TK_ = 32;         // k-tile (one MFMA K)
constexpr int NKT_ = N_ / TK_;  // 64 k-tiles

typedef __bf16 bf16x8 __attribute__((ext_vector_type(8)));
typedef float floatx4 __attribute__((ext_vector_type(4)));

__device__ __forceinline__ unsigned short f2b(float f) {
    unsigned int u = __float_as_uint(f);
    return (unsigned short)((u + 0x7fffu + ((u >> 16) & 1u)) >> 16);
}
__device__ __forceinline__ float lrelu(float x) { return fmaxf(x, 0.2f * x); }

// ---------------------------------------------------------------- embedding
// state0B[bn][h] (bf16) = nodes @ W_emb + b_emb
__global__ __launch_bounds__(256) void embed_kernel(
        const float* __restrict__ nodes, const float* __restrict__ W_emb,
        const float* __restrict__ b_emb, unsigned short* __restrict__ state0B) {
    int t = threadIdx.x;
    int r = t >> 6, h = t & 63;
    int bn = blockIdx.x * 4 + r;
    __shared__ float sn[4][I_];
    if (t < 4 * I_) {
        int rr = t / I_, ii = t % I_;
        sn[rr][ii] = nodes[(size_t)(blockIdx.x * 4 + rr) * I_ + ii];
    }
    __syncthreads();
    float acc = b_emb[h];
    #pragma unroll
    for (int i = 0; i < I_; ++i) acc += sn[r][i] * W_emb[i * H_ + h];
    state0B[(size_t)bn * H_ + h] = f2b(acc);
}

// ------------------------------------------------ Wf transpose/pack to bf16
// WfB[c][n][k] = Wf[c][k][n]  (bf16). B-fragment load = 16B contiguous in k.
template <int DIN>
__global__ __launch_bounds__(256) void wf_pack_kernel(
        const float* __restrict__ Wf, unsigned short* __restrict__ WfB) {
    int o = blockIdx.x * 256 + threadIdx.x;     // EH*64*DIN
    int k = o & (DIN - 1);
    int n = (o / DIN) & 63;
    int c = o / (DIN * 64);
    WfB[o] = f2b(Wf[((size_t)c * DIN + k) * 64 + n]);
}

// ---------------------------------------------------- Wh + a1/a2 via MFMA
// Block: 16 bn rows; wave wv = c. Wh[c,bn,n] = sum_k stateB[bn,k]*WfB[c,n,k].
// Outputs: WhB in mac B-fragment layout + a1/a2 row dots (shfl butterfly).
template <int DIN>
__global__ __launch_bounds__(256) void wh_a_mfma_kernel(
        const unsigned short* __restrict__ stateB, const unsigned short* __restrict__ WfB,
        const float* __restrict__ w1, const float* __restrict__ b1,
        const float* __restrict__ w2, const float* __restrict__ b2,
        unsigned short* __restrict__ WhB, float* __restrict__ a1,
        float* __restrict__ a2) {
    int t = threadIdx.x;
    int lane = t & 63, wv = t >> 6;             // wv = c
    int col = lane & 15, qd = lane >> 4;
    int bn0 = blockIdx.x * TI_;                 // grid BN/16 = 512
    int b = bn0 >> 11;

    floatx4 acc[4] = {{0,0,0,0},{0,0,0,0},{0,0,0,0},{0,0,0,0}};
    const unsigned short* __restrict__ ap = stateB + (size_t)(bn0 + col) * DIN + qd * 8;
    const unsigned short* __restrict__ bp = WfB + ((size_t)(wv * 64 + col) * DIN + qd * 8);
    #pragma unroll
    for (int k0 = 0; k0 < DIN; k0 += 32) {
        bf16x8 af = *(const bf16x8*)(ap + k0);
        #pragma unroll
        for (int nt = 0; nt < 4; ++nt) {
            bf16x8 bf = *(const bf16x8*)(bp + (size_t)nt * 16 * DIN + k0);
            acc[nt] = __builtin_amdgcn_mfma_f32_16x16x32_bf16(af, bf, acc[nt], 0, 0, 0);
        }
    }
    // acc[nt][r] = Wh[bn0 + qd*4 + r][nt*16 + col]
    // WhB store: (((c*B+b)*256 + nb)*64 + d)*8 + (n&7); rows qd*4+r
    int nb = ((bn0 & 2047) >> 3) + (qd >> 1);
    #pragma unroll
    for (int nt = 0; nt < 4; ++nt) {
        unsigned int lo = (unsigned int)f2b(acc[nt][0]) | ((unsigned int)f2b(acc[nt][1]) << 16);
        unsigned int hi = (unsigned int)f2b(acc[nt][2]) | ((unsigned int)f2b(acc[nt][3]) << 16);
        uint2 v = make_uint2(lo, hi);
        *(uint2*)(WhB + ((((size_t)(wv * B_ + b) * 256 + nb) * 64 + nt * 16 + col) * 8
                         + (qd & 1) * 4)) = v;
    }
    // a1/a2: p[r] = sum_n Wh[row][n] * w(n); butterfly over col lanes
    float p1[4] = {}, p2[4] = {};
    #pragma unroll
    for (int nt = 0; nt < 4; ++nt) {
        float w1n = w1[wv * H_ + nt * 16 + col];
        float w2n = w2[wv * H_ + nt * 16 + col];
        #pragma unroll
        for (int r = 0; r < 4; ++r) {
            p1[r] += acc[nt][r] * w1n;
            p2[r] += acc[nt][r] * w2n;
        }
    }
    #pragma unroll
    for (int m = 1; m < 16; m <<= 1)
        #pragma unroll
        for (int r = 0; r < 4; ++r) {
            p1[r] += __shfl_xor(p1[r], m, 64);
            p2[r] += __shfl_xor(p2[r], m, 64);
        }
    if (col == 0) {
        float b1c = b1[wv], b2c = b2[wv];
        #pragma unroll
        for (int r = 0; r < 4; ++r) {
            a1[(size_t)wv * BN_ + bn0 + qd * 4 + r] = p1[r] + b1c;
            a2[(size_t)wv * BN_ + bn0 + qd * 4 + r] = p2[r] + b2c;
        }
    }
}

// -------------------------------------------------- column softmax stats
// 1-exp online update: if l>m: s = s*e+1 else s += e, e = exp(-|l-m|)
__global__ __launch_bounds__(256) void stats_kernel(
        const float* __restrict__ edges, const float* __restrict__ a1,
        const float* __restrict__ a2, float* __restrict__ pm, float* __restrict__ ps) {
    int blk = blockIdx.x;                       // B*NC*(N/256) = 512
    int jt = blk & 7;
    int ic = (blk >> 3) & (NC_ - 1);
    int b  = blk >> 7;
    int t = threadIdx.x;
    int j = jt * 256 + t;
    __shared__ float sa1[EH_][CH_];
    for (int q = t; q < EH_ * CH_; q += 256) {
        int cc = q / CH_, ii = q % CH_;
        sa1[cc][ii] = a1[(size_t)cc * BN_ + b * N_ + ic * CH_ + ii];
    }
    __syncthreads();
    float a2v[EH_], m[EH_], s[EH_];
    #pragma unroll
    for (int cc = 0; cc < EH_; ++cc) {
        a2v[cc] = a2[(size_t)cc * BN_ + b * N_ + j];
        m[cc] = -1e30f; s[cc] = 0.f;
    }
    const float2* __restrict__ ep = (const float2*)edges + ((size_t)(b * N_ + ic * CH_)) * N_ + j;
    #pragma unroll 2
    for (int ii = 0; ii < CH_; ++ii) {
        float2 u = ep[(size_t)ii * N_];
        #pragma unroll
        for (int cc = 0; cc < EH_; ++cc) {
            float x = sa1[cc][ii] + a2v[cc];
            float l = lrelu(x) + ((cc < 2) ? u.x : u.y);
            float mo = m[cc];
            float e = __expf(-fabsf(l - mo));
            bool gt = l > mo;
            float tl = gt ? e : 1.f;
            float ua = gt ? 1.f : e;
            s[cc] = fmaf(s[cc], tl, ua);
            m[cc] = fmaxf(mo, l);
        }
    }
    #pragma unroll
    for (int cc = 0; cc < EH_; ++cc) {
        size_t q = ((size_t)ic * EH_ + cc) * BN_ + b * N_ + j;
        pm[q] = m[cc]; ps[q] = s[cc];
    }
}

// combine partials -> za[c][bn] = (Z = m + lnS, a2)
__global__ __launch_bounds__(256) void combine_kernel(
        const float* __restrict__ pm, const float* __restrict__ ps,
        const float* __restrict__ a2, float2* __restrict__ za) {
    int q = blockIdx.x * 256 + threadIdx.x;     // EH*BN = 32768
    float M = -1e30f;
    #pragma unroll
    for (int ic = 0; ic < NC_; ++ic) M = fmaxf(M, pm[(size_t)ic * EH_ * BN_ + q]);
    float S = 0.f;
    #pragma unroll
    for (int ic = 0; ic < NC_; ++ic)
        S += ps[(size_t)ic * EH_ * BN_ + q] * __expf(pm[(size_t)ic * EH_ * BN_ + q] - M);
    za[q] = make_float2(M + __logf(S), a2[q]);
}

// ------------------------------------------------------------- MFMA MAC
// LAST=0: out = state1B (ushort bf16, row-major [bn][D1]); LAST=1: out = state2 (float)
template <int LAST>
__global__ __launch_bounds__(256, 4) void mac_kernel(
        const float* __restrict__ edges, const float* __restrict__ a1,
        const float2* __restrict__ za, const unsigned short* __restrict__ WhB,
        const float* __restrict__ bias, void* __restrict__ outv) {
    int t = threadIdx.x;                    // 256
    int blk = blockIdx.x;                   // B*(N/16) = 512
    int b = blk >> 7;
    int i0 = (blk & 127) * TI_;
    int lane = t & 63, wv = t >> 6;         // wave id = c
    int ai = t >> 4;                        // att row 0..15
    int ak = (t & 15) * 2;                  // att k (even) 0..30
    int qd = lane >> 4;
    int col = lane & 15;

    __shared__ unsigned short satt[2][EH_][TI_][40];
    __shared__ float2 szq[2][EH_][TK_];
    __shared__ float sred[EH_][TI_][H_];

    float a1v[EH_];
    #pragma unroll
    for (int cc = 0; cc < EH_; ++cc)
        a1v[cc] = a1[(size_t)cc * BN_ + b * N_ + i0 + ai];

    const float4* __restrict__ ep =
        (const float4*)edges + (size_t)(b * N_ + i0 + ai) * (N_ >> 1);
    float4 ev0 = ep[(ak >> 1)];
    float4 ev1 = ep[(TK_ >> 1) + (ak >> 1)];
    if (t < 128) {
        int cc = t >> 5, kk = t & 31;
        szq[0][cc][kk] = za[(size_t)cc * BN_ + b * N_ + kk];
    }
    const unsigned short* __restrict__ whb0 =
        WhB + (size_t)(wv * B_ + b) * (256 * 512);
    bf16x8 bcur[4], bnxt[4];
    #pragma unroll
    for (int nt = 0; nt < 4; ++nt)
        bcur[nt] = *(const bf16x8*)(whb0 + ((size_t)(0 + qd) * 64 + nt * 16 + col) * 8);

    floatx4 acc[4] = {{0,0,0,0},{0,0,0,0},{0,0,0,0},{0,0,0,0}};
    __syncthreads();

    for (int kt = 0; kt < NKT_; ++kt) {
        int cur = kt & 1, nxt = cur ^ 1;
        int k0n = ((kt + 1) & (NKT_ - 1)) * TK_;
        if (t < 128) {
            int cc = t >> 5, kk = t & 31;
            szq[nxt][cc][kk] = za[(size_t)cc * BN_ + b * N_ + k0n + kk];
        }
        #pragma unroll
        for (int cc = 0; cc < EH_; ++cc) {
            float2 z0 = szq[cur][cc][ak];
            float2 z1 = szq[cur][cc][ak + 1];
            float e0 = (cc < 2) ? ev0.x : ev0.y;
            float e1 = (cc < 2) ? ev0.z : ev0.w;
            float at0 = __expf(lrelu(a1v[cc] + z0.y) + e0 - z0.x);
            float at1 = __expf(lrelu(a1v[cc] + z1.y) + e1 - z1.x);
            unsigned int p = (unsigned int)f2b(at0) | ((unsigned int)f2b(at1) << 16);
            *(unsigned int*)&satt[cur][cc][ai][ak] = p;
        }
        float4 ev2 = ep[((kt + 2) & (NKT_ - 1)) * (TK_ >> 1) + (ak >> 1)];
        __syncthreads();
        int kb = ((kt + 1) & (NKT_ - 1)) * (TK_ >> 3);
        #pragma unroll
        for (int nt = 0; nt < 4; ++nt)
            bnxt[nt] = *(const bf16x8*)(whb0 + ((size_t)(kb + qd) * 64 + nt * 16 + col) * 8);
        bf16x8 af = *(const bf16x8*)&satt[cur][wv][col][qd * 8];
        #pragma unroll
        for (int nt = 0; nt < 4; ++nt)
            acc[nt] = __builtin_amdgcn_mfma_f32_16x16x32_bf16(af, bcur[nt], acc[nt], 0, 0, 0);
        #pragma unroll
        for (int nt = 0; nt < 4; ++nt) bcur[nt] = bnxt[nt];
        ev0 = ev1; ev1 = ev2;
    }

    if (LAST) {
        float* out = (float*)outv;
        #pragma unroll
        for (int nt = 0; nt < 4; ++nt) {
            float bv = bias[(wv & 1) * H_ + nt * 16 + col];
            #pragma unroll
            for (int r = 0; r < 4; ++r) {
                float x = acc[nt][r] + bv;
                sred[wv][qd * 4 + r][nt * 16 + col] = x > 0.f ? x : (__expf(x) - 1.f);
            }
        }
        __syncthreads();
        #pragma unroll
        for (int q = 0; q < 4; ++q) {
            int p = t + q * 256;
            int r = p >> 6, d = p & 63;
            float s = sred[0][r][d] + sred[1][r][d] + sred[2][r][d] + sred[3][r][d];
            out[((size_t)(b * N_ + i0 + r)) * H_ + d] = s * 0.25f;
        }
    } else {
        unsigned short* out = (unsigned short*)outv;
        #pragma unroll
        for (int nt = 0; nt < 4; ++nt) {
            float bv = bias[(wv & 1) * H_ + nt * 16 + col];
            #pragma unroll
            for (int r = 0; r < 4; ++r)
                out[((size_t)(b * N_ + i0 + qd * 4 + r)) * D1_ + wv * H_ + nt * 16 + col] =
                    f2b(acc[nt][r] + bv);
        }
    }
}

// ------------------------------------------------------------- final output
__global__ __launch_bounds__(256) void out_kernel(
        const float* __restrict__ state2, const float* __restrict__ W_out,
        const float* __restrict__ b_out, float* __restrict__ out) {
    int b = blockIdx.x, t = threadIdx.x;
    int d = t & 63, nc = t >> 6;
    float psum = 0.f;
    const float* sp = state2 + ((size_t)b * N_ + nc * (N_ / 4)) * H_ + d;
    for (int n = 0; n < N_ / 4; ++n) psum += sp[(size_t)n * H_];
    __shared__ float red[4][H_];
    red[nc][d] = psum;
    __syncthreads();
    if (t < H_) red[0][d] = red[0][d] + red[1][d] + red[2][d] + red[3][d];
    __syncthreads();
    if (t < O_) {
        float acc = b_out[t];
        #pragma unroll 8
        for (int dd = 0; dd < H_; ++dd)
            acc += (red[0][dd] * (1.f / N_)) * W_out[dd * O_ + t];
        out[b * O_ + t] = acc;
    }
}

extern "C" void kernel_launch(void* const* d_in, const int* in_sizes, int n_in,
                              void* d_out, int out_size, void* d_ws, size_t ws_size,
                              hipStream_t stream) {
    const float* nodes = (const float*)d_in[0];
    const float* edges = (const float*)d_in[1];
    const float* W_emb = (const float*)d_in[2];
    const float* b_emb = (const float*)d_in[3];
    const float* Wf0   = (const float*)d_in[4];
    const float* w1_0  = (const float*)d_in[5];
    const float* b1_0  = (const float*)d_in[6];
    const float* w2_0  = (const float*)d_in[7];
    const float* b2_0  = (const float*)d_in[8];
    const float* bias0 = (const float*)d_in[9];
    const float* Wf1   = (const float*)d_in[10];
    const float* w1_1  = (const float*)d_in[11];
    const float* b1_1  = (const float*)d_in[12];
    const float* w2_1  = (const float*)d_in[13];
    const float* b2_1  = (const float*)d_in[14];
    const float* bias1 = (const float*)d_in[15];
    const float* W_out = (const float*)d_in[16];
    const float* b_out = (const float*)d_in[17];

    float* ws = (float*)d_ws;
    unsigned short* state0B = (unsigned short*)ws;                  // BN*64  ushort = 262144 fl
    unsigned short* state1B = (unsigned short*)(ws + 262144);       // BN*256 ushort = 1048576 fl
    float* state2 = ws + 262144 + 1048576;                          // BN*64 fp32
    unsigned short* WhB  = (unsigned short*)(state2 + 524288);      // 4*BN*64 ushort = 1048576 fl
    unsigned short* WfB0 = (unsigned short*)(state2 + 524288 + 1048576);  // 16384 us = 8192 fl
    unsigned short* WfB1 = WfB0 + 16384;                            // 65536 us = 32768 fl
    float* a1   = state2 + 524288 + 1048576 + 8192 + 32768;
    float* a2   = a1 + 32768;
    float* pm   = a2 + 32768;                                       // 524288
    float* psum = pm + 524288;                                      // 524288
    float2* za  = (float2*)(psum + 524288);                         // 65536 fl

    wf_pack_kernel<H_><<<EH_ * 64 * H_ / 256, 256, 0, stream>>>(Wf0, WfB0);
    wf_pack_kernel<D1_><<<EH_ * 64 * D1_ / 256, 256, 0, stream>>>(Wf1, WfB1);
    embed_kernel<<<BN_ / 4, 256, 0, stream>>>(nodes, W_emb, b_emb, state0B);

    // ---- layer 0
    wh_a_mfma_kernel<H_><<<BN_ / TI_, 256, 0, stream>>>(state0B, WfB0, w1_0, b1_0,
                                                        w2_0, b2_0, WhB, a1, a2);
    stats_kernel<<<B_ * NC_ * (N_ / 256), 256, 0, stream>>>(edges, a1, a2, pm, psum);
    combine_kernel<<<EH_ * BN_ / 256, 256, 0, stream>>>(pm, psum, a2, za);
    mac_kernel<0><<<B_ * (N_ / TI_), 256, 0, stream>>>(edges, a1, za, WhB, bias0, state1B);
    // ---- layer 1
    wh_a_mfma_kernel<D1_><<<BN_ / TI_, 256, 0, stream>>>(state1B, WfB1, w1_1, b1_1,
                                                         w2_1, b2_1, WhB, a1, a2);
    stats_kernel<<<B_ * NC_ * (N_ / 256), 256, 0, stream>>>(edges, a1, a2, pm, psum);
    combine_kernel<<<EH_ * BN_ / 256, 256, 0, stream>>>(pm, psum, a2, za);
    mac_kernel<1><<<B_ * (N_ / TI_), 256, 0, stream>>>(edges, a1, za, WhB, bias1, state2);

    out_kernel<<<B_, 256, 0, stream>>>(state2, W_out, b_out, (float*)d_out);
}